// Round 6
// baseline (446.933 us; speedup 1.0000x reference)
//
#include <hip/hip_runtime.h>
#include <math.h>

// CapsuleLayer: u = x@W via split-precision f16 MFMA (xh@Wh + xl@Wh + xh@Wl),
// 32x32x16, LDS double-buffered B staging, A prefetched in registers.
// R6 = R5 with the reduction fix: lane-bit-5 crossing MUST be ds_bpermute
// (__shfl_xor(x,32)); ds_swizzle BitMode xor_mask is 5 bits (max 31) and
// DPP row ops stay within 16-lane rows. R5's swz_xor<32> was invalid.
//
// x: [32768,512] fp32  W: [512,512] fp32  v: [32768,32] fp32
// prep_w: W[k][n] -> Wh/Wl tiled [kt][n][k%16] f16 in d_ws (1 MB).
//
// Main: block = 512 thr (8 waves), tile 128 rows x 512 cols, grid 256.
// Wave (r=w>>2, c=w&3): rows r*64 + mf*32, cols c*128 (4 n-tiles of 32).
// acc = 2x4x16 fp32. Per kt (BK=16): 1 barrier, 4 DMA stage, 4 A-loads,
// 8 ds_read_b128, 24 MFMA. Epilogue: 4 phases of 32 rows via u_lds.

#define BATCH   32768
#define KDIM    512
#define NDIM    512
#define OUT_DIM 32
#define EPS_F   1e-8f
#define NKT     32            // K tiles of 16

typedef _Float16 half8  __attribute__((ext_vector_type(8)));
typedef float   floatx4 __attribute__((ext_vector_type(4)));
typedef float  floatx16 __attribute__((ext_vector_type(16)));

// ---- cross-lane helpers ----
template <int CTRL>
__device__ __forceinline__ float dpp_mov(float x) {
    return __int_as_float(__builtin_amdgcn_mov_dpp(__float_as_int(x), CTRL, 0xF, 0xF, true));
}
template <int XMASK>   // XMASK <= 31: ds_swizzle BitMode xor (within 32-lane group)
__device__ __forceinline__ float swz_xor(float x) {
    return __int_as_float(__builtin_amdgcn_ds_swizzle(__float_as_int(x), (XMASK << 10) | 31));
}
#define ROR4  0x124  // row_ror:4  (16-lane row, cyclic)
#define ROR8  0x128  // row_ror:8
#define QXOR1 0xB1   // quad_perm [1,0,3,2] = xor 1
#define QXOR2 0x4E   // quad_perm [2,3,0,1] = xor 2

// allreduce over capsule lanes (lane bits 2..5):
// bits 2,3 via DPP row rotations; bit 4 via ds_swizzle xor16; bit 5 via bpermute
__device__ __forceinline__ float cap_sum(float x) {
    x += dpp_mov<ROR4>(x);
    x += dpp_mov<ROR8>(x);
    x += swz_xor<16>(x);
    x += __shfl_xor(x, 32);
    return x;
}
__device__ __forceinline__ float cap_max(float x) {
    x = fmaxf(x, dpp_mov<ROR4>(x));
    x = fmaxf(x, dpp_mov<ROR8>(x));
    x = fmaxf(x, swz_xor<16>(x));
    x = fmaxf(x, __shfl_xor(x, 32));
    return x;
}
// allreduce over dim-group lanes (lane bits 0..1): quad_perm only (VALU)
__device__ __forceinline__ float dg_sum(float x) {
    x += dpp_mov<QXOR1>(x);
    x += dpp_mov<QXOR2>(x);
    return x;
}

// ---- prep: W[k][n] fp32 -> Wh/Wl [kt][n][k%16] f16 hi/lo split ----
__global__ void prep_w(const float* __restrict__ W, _Float16* __restrict__ Wh,
                       _Float16* __restrict__ Wl) {
    __shared__ float tile[32][33];
    const int tx = threadIdx.x, ty = threadIdx.y;      // block (32, 8)
    const int n0 = blockIdx.x * 32, k0 = blockIdx.y * 32;
#pragma unroll
    for (int i = 0; i < 4; ++i)
        tile[ty + 8 * i][tx] = W[(size_t)(k0 + ty + 8 * i) * NDIM + n0 + tx];
    __syncthreads();
#pragma unroll
    for (int i = 0; i < 4; ++i) {
        const int k = k0 + tx, n = n0 + ty + 8 * i;
        const float v = tile[tx][ty + 8 * i];          // = W[k][n]
        const _Float16 h = (_Float16)v;
        const _Float16 l = (_Float16)(v - (float)h);
        const size_t off = (size_t)(k >> 4) * (NDIM * 16) + (size_t)n * 16 + (k & 15);
        Wh[off] = h;
        Wl[off] = l;
    }
}

__device__ __forceinline__ void ld_g2l_16(void* lds_base_uniform, const void* g) {
    __builtin_amdgcn_global_load_lds(
        (const __attribute__((address_space(1))) void*)g,
        (__attribute__((address_space(3))) void*)lds_base_uniform, 16, 0, 0);
}

__global__ __launch_bounds__(512, 2)
void capsule_mfma(const float* __restrict__ x, const _Float16* __restrict__ Wh,
                  const _Float16* __restrict__ Wl, float* __restrict__ out) {
    __shared__ __align__(16) char smem[66560];         // max(Bs 64K, u_lds 66.56K)
    _Float16 (*Bs)[2][NDIM][16] = (_Float16 (*)[2][NDIM][16])smem;  // [buf][h/l][n][k']
    float (*u_lds)[520] = (float (*)[520])smem;

    const int tid  = threadIdx.x;
    const int w    = tid >> 6;          // wave 0..7
    const int lane = tid & 63;
    const int r = w >> 2, c = w & 3;    // row-half / col-group
    const int ln = lane & 31, q = lane >> 5;
    const int rowBlk = blockIdx.x * 128;
    const int R0 = rowBlk + r * 64;
    const int C0 = c * 128;

    floatx16 acc[2][4];
#pragma unroll
    for (int mf = 0; mf < 2; ++mf)
#pragma unroll
        for (int nt = 0; nt < 4; ++nt)
#pragma unroll
            for (int i = 0; i < 16; ++i) acc[mf][nt][i] = 0.f;

    // A frag: row = ln (+32 for mf=1), k = q*8 + j
    const float* aptr0 = x + (size_t)(R0 + ln) * KDIM + q * 8;
    const float* aptr1 = aptr0 + (size_t)32 * KDIM;

    // B staging: wave w copies n in [w*64, w*64+64) for h and l
    const int nseg = w * 64;

    // ---- stage kt=0, prefetch A(0) ----
    ld_g2l_16(&Bs[0][0][nseg][0],      Wh + (size_t)nseg * 16 + lane * 8);
    ld_g2l_16(&Bs[0][0][nseg + 32][0], Wh + (size_t)(nseg + 32) * 16 + lane * 8);
    ld_g2l_16(&Bs[0][1][nseg][0],      Wl + (size_t)nseg * 16 + lane * 8);
    ld_g2l_16(&Bs[0][1][nseg + 32][0], Wl + (size_t)(nseg + 32) * 16 + lane * 8);
    floatx4 a[2][2];
    a[0][0] = *(const floatx4*)(aptr0);
    a[0][1] = *(const floatx4*)(aptr0 + 4);
    a[1][0] = *(const floatx4*)(aptr1);
    a[1][1] = *(const floatx4*)(aptr1 + 4);

#pragma unroll 2
    for (int kt = 0; kt < NKT; ++kt) {
        __syncthreads();               // stage(kt) complete; buf^1 readers done
        const int buf = kt & 1;
        if (kt + 1 < NKT) {            // stage(kt+1) into other buffer (async)
            const size_t g = (size_t)(kt + 1) * (NDIM * 16);
            ld_g2l_16(&Bs[buf ^ 1][0][nseg][0],      Wh + g + (size_t)nseg * 16 + lane * 8);
            ld_g2l_16(&Bs[buf ^ 1][0][nseg + 32][0], Wh + g + (size_t)(nseg + 32) * 16 + lane * 8);
            ld_g2l_16(&Bs[buf ^ 1][1][nseg][0],      Wl + g + (size_t)nseg * 16 + lane * 8);
            ld_g2l_16(&Bs[buf ^ 1][1][nseg + 32][0], Wl + g + (size_t)(nseg + 32) * 16 + lane * 8);
        }
        floatx4 pr[2][2];              // A prefetch for kt+1
        if (kt + 1 < NKT) {
            pr[0][0] = *(const floatx4*)(aptr0 + (kt + 1) * 16);
            pr[0][1] = *(const floatx4*)(aptr0 + (kt + 1) * 16 + 4);
            pr[1][0] = *(const floatx4*)(aptr1 + (kt + 1) * 16);
            pr[1][1] = *(const floatx4*)(aptr1 + (kt + 1) * 16 + 4);
        }
        // convert A(kt) to f16 hi/lo frags
        half8 ah[2], al[2];
#pragma unroll
        for (int mf = 0; mf < 2; ++mf) {
            const float av[8] = {a[mf][0][0], a[mf][0][1], a[mf][0][2], a[mf][0][3],
                                 a[mf][1][0], a[mf][1][1], a[mf][1][2], a[mf][1][3]};
#pragma unroll
            for (int j = 0; j < 8; ++j) {
                const _Float16 h = (_Float16)av[j];
                ah[mf][j] = h;
                al[mf][j] = (_Float16)(av[j] - (float)h);
            }
        }
#pragma unroll
        for (int nt = 0; nt < 4; ++nt) {
            const half8 bh = *(const half8*)&Bs[buf][0][C0 + nt * 32 + ln][q * 8];
            const half8 bl = *(const half8*)&Bs[buf][1][C0 + nt * 32 + ln][q * 8];
#pragma unroll
            for (int mf = 0; mf < 2; ++mf) {
                acc[mf][nt] = __builtin_amdgcn_mfma_f32_32x32x16_f16(ah[mf], bh, acc[mf][nt], 0, 0, 0);
                acc[mf][nt] = __builtin_amdgcn_mfma_f32_32x32x16_f16(al[mf], bh, acc[mf][nt], 0, 0, 0);
                acc[mf][nt] = __builtin_amdgcn_mfma_f32_32x32x16_f16(ah[mf], bl, acc[mf][nt], 0, 0, 0);
            }
        }
        if (kt + 1 < NKT) {
#pragma unroll
            for (int mf = 0; mf < 2; ++mf) { a[mf][0] = pr[mf][0]; a[mf][1] = pr[mf][1]; }
        }
    }

    // ---- epilogue: four 32-row phases; acc -> u_lds fp32, then routing ----
    // C/D layout 32x32: col = ln, row = (reg&3) + 8*(reg>>2) + 4*q
    // routing lane map: cap = lane>>2 (bits 2..5), dgrp = lane&3 (bits 0..1)
    const int dgrp = lane & 3;
    for (int p = 0; p < 4; ++p) {
        __syncthreads();               // previous-phase reads / K-loop reads done
        if (r == (p >> 1)) {
            const int mf = p & 1;
#pragma unroll
            for (int nt = 0; nt < 4; ++nt)
#pragma unroll
                for (int reg = 0; reg < 16; ++reg)
                    u_lds[(reg & 3) + 8 * (reg >> 2) + 4 * q][C0 + nt * 32 + ln] = acc[mf][nt][reg];
        }
        __syncthreads();
#pragma unroll 1
        for (int ri = 0; ri < 4; ++ri) {
            const int rl = w * 4 + ri;               // local row 0..31
            const floatx4 ua = *(const floatx4*)&u_lds[rl][lane * 8];
            const floatx4 ub = *(const floatx4*)&u_lds[rl][lane * 8 + 4];
            const float u8[8] = {ua[0], ua[1], ua[2], ua[3],
                                 ub[0], ub[1], ub[2], ub[3]};
            float b_own = 0.f;
            float v[8];
#pragma unroll
            for (int it = 0; it < 3; ++it) {
                float c_own;
                if (it == 0) {
                    c_own = 1.0f / 16.0f;            // softmax of zeros
                } else {
                    const float m = cap_max(b_own);
                    const float e = __expf(b_own - m);
                    const float ssum = cap_sum(e);
                    c_own = e / ssum;
                }
                float s[8];
#pragma unroll
                for (int j = 0; j < 8; ++j) s[j] = c_own * u8[j];
                // allreduce each s[j] over capsules, steps interleaved for ILP
#pragma unroll
                for (int j = 0; j < 8; ++j) s[j] += dpp_mov<ROR4>(s[j]);
#pragma unroll
                for (int j = 0; j < 8; ++j) s[j] += dpp_mov<ROR8>(s[j]);
#pragma unroll
                for (int j = 0; j < 8; ++j) s[j] += swz_xor<16>(s[j]);
#pragma unroll
                for (int j = 0; j < 8; ++j) s[j] += __shfl_xor(s[j], 32);
                float nrm = 0.f;
#pragma unroll
                for (int j = 0; j < 8; ++j) nrm = fmaf(s[j], s[j], nrm);
                nrm = dg_sum(nrm);
                const float scale = nrm / ((1.f + nrm) * (sqrtf(nrm) + EPS_F));
#pragma unroll
                for (int j = 0; j < 8; ++j) v[j] = scale * s[j];
                if (it < 2) {
                    float dot = 0.f;
#pragma unroll
                    for (int j = 0; j < 8; ++j) dot = fmaf(u8[j], v[j], dot);
                    dot = dg_sum(dot);
                    b_own += dot;
                }
            }
            if (lane < 4) {
                float4* o = (float4*)(out + (size_t)(rowBlk + p * 32 + rl) * OUT_DIM
                                      + dgrp * 8);
                o[0] = make_float4(v[0], v[1], v[2], v[3]);
                o[1] = make_float4(v[4], v[5], v[6], v[7]);
            }
        }
    }
}

extern "C" void kernel_launch(void* const* d_in, const int* in_sizes, int n_in,
                              void* d_out, int out_size, void* d_ws, size_t ws_size,
                              hipStream_t stream) {
    const float* x = (const float*)d_in[0];   // [32768, 512]
    const float* W = (const float*)d_in[1];   // [512, 512]
    float* out = (float*)d_out;               // [32768, 32]
    _Float16* Wh = (_Float16*)d_ws;           // [32][512][16] f16 tiled
    _Float16* Wl = Wh + (size_t)NDIM * KDIM;

    prep_w<<<dim3(16, 16), dim3(32, 8), 0, stream>>>(W, Wh, Wl);
    capsule_mfma<<<dim3(BATCH / 128), dim3(512), 0, stream>>>(x, Wh, Wl, out);
}

// Round 7
// 167.586 us; speedup vs baseline: 2.6669x; 2.6669x over previous
//
#include <hip/hip_runtime.h>
#include <math.h>

// CapsuleLayer: u = x@W via split-precision f16 MFMA (xh@Wh + xl@Wh + xh@Wl),
// 32x32x16, LDS double-buffered B staging, A prefetched in registers.
// R7 = R6 + CRITICAL FIX: epilogue phase loop must be #pragma unroll so
// acc[mf] is compile-time indexed. R6 left it a runtime loop -> the whole
// acc[2][4][16] was demoted to scratch -> 2.2 GB of spill writes (rocprof
// WRITE_SIZE), 405 us. Never index acc[] with a runtime value.
//
// x: [32768,512] fp32  W: [512,512] fp32  v: [32768,32] fp32
// prep_w: W[k][n] -> Wh/Wl tiled [kt][n][k%16] f16 in d_ws (1 MB).
//
// Main: block = 512 thr (8 waves), tile 128 rows x 512 cols, grid 256.
// Wave (r=w>>2, c=w&3): rows r*64 + mf*32, cols c*128 (4 n-tiles of 32).
// acc = 2x4x16 fp32. Per kt (BK=16): 1 barrier, 4 DMA stage, 4 A-loads,
// 8 ds_read_b128, 24 MFMA. Epilogue: 4 phases of 32 rows via u_lds.

#define BATCH   32768
#define KDIM    512
#define NDIM    512
#define OUT_DIM 32
#define EPS_F   1e-8f
#define NKT     32            // K tiles of 16

typedef _Float16 half8  __attribute__((ext_vector_type(8)));
typedef float   floatx4 __attribute__((ext_vector_type(4)));
typedef float  floatx16 __attribute__((ext_vector_type(16)));

// ---- cross-lane helpers ----
template <int CTRL>
__device__ __forceinline__ float dpp_mov(float x) {
    return __int_as_float(__builtin_amdgcn_mov_dpp(__float_as_int(x), CTRL, 0xF, 0xF, true));
}
template <int XMASK>   // XMASK <= 31: ds_swizzle BitMode xor (within 32-lane group)
__device__ __forceinline__ float swz_xor(float x) {
    return __int_as_float(__builtin_amdgcn_ds_swizzle(__float_as_int(x), (XMASK << 10) | 31));
}
#define ROR4  0x124  // row_ror:4  (16-lane row, cyclic)
#define ROR8  0x128  // row_ror:8
#define QXOR1 0xB1   // quad_perm [1,0,3,2] = xor 1
#define QXOR2 0x4E   // quad_perm [2,3,0,1] = xor 2

// allreduce over capsule lanes (lane bits 2..5):
// bits 2,3 via DPP row rotations; bit 4 via ds_swizzle xor16; bit 5 via bpermute
__device__ __forceinline__ float cap_sum(float x) {
    x += dpp_mov<ROR4>(x);
    x += dpp_mov<ROR8>(x);
    x += swz_xor<16>(x);
    x += __shfl_xor(x, 32);
    return x;
}
__device__ __forceinline__ float cap_max(float x) {
    x = fmaxf(x, dpp_mov<ROR4>(x));
    x = fmaxf(x, dpp_mov<ROR8>(x));
    x = fmaxf(x, swz_xor<16>(x));
    x = fmaxf(x, __shfl_xor(x, 32));
    return x;
}
// allreduce over dim-group lanes (lane bits 0..1): quad_perm only (VALU)
__device__ __forceinline__ float dg_sum(float x) {
    x += dpp_mov<QXOR1>(x);
    x += dpp_mov<QXOR2>(x);
    return x;
}

// ---- prep: W[k][n] fp32 -> Wh/Wl [kt][n][k%16] f16 hi/lo split ----
__global__ void prep_w(const float* __restrict__ W, _Float16* __restrict__ Wh,
                       _Float16* __restrict__ Wl) {
    __shared__ float tile[32][33];
    const int tx = threadIdx.x, ty = threadIdx.y;      // block (32, 8)
    const int n0 = blockIdx.x * 32, k0 = blockIdx.y * 32;
#pragma unroll
    for (int i = 0; i < 4; ++i)
        tile[ty + 8 * i][tx] = W[(size_t)(k0 + ty + 8 * i) * NDIM + n0 + tx];
    __syncthreads();
#pragma unroll
    for (int i = 0; i < 4; ++i) {
        const int k = k0 + tx, n = n0 + ty + 8 * i;
        const float v = tile[tx][ty + 8 * i];          // = W[k][n]
        const _Float16 h = (_Float16)v;
        const _Float16 l = (_Float16)(v - (float)h);
        const size_t off = (size_t)(k >> 4) * (NDIM * 16) + (size_t)n * 16 + (k & 15);
        Wh[off] = h;
        Wl[off] = l;
    }
}

__device__ __forceinline__ void ld_g2l_16(void* lds_base_uniform, const void* g) {
    __builtin_amdgcn_global_load_lds(
        (const __attribute__((address_space(1))) void*)g,
        (__attribute__((address_space(3))) void*)lds_base_uniform, 16, 0, 0);
}

__global__ __launch_bounds__(512, 2)
void capsule_mfma(const float* __restrict__ x, const _Float16* __restrict__ Wh,
                  const _Float16* __restrict__ Wl, float* __restrict__ out) {
    __shared__ __align__(16) char smem[66560];         // max(Bs 64K, u_lds 66.56K)
    _Float16 (*Bs)[2][NDIM][16] = (_Float16 (*)[2][NDIM][16])smem;  // [buf][h/l][n][k']
    float (*u_lds)[520] = (float (*)[520])smem;

    const int tid  = threadIdx.x;
    const int w    = tid >> 6;          // wave 0..7
    const int lane = tid & 63;
    const int r = w >> 2, c = w & 3;    // row-half / col-group
    const int ln = lane & 31, q = lane >> 5;
    const int rowBlk = blockIdx.x * 128;
    const int R0 = rowBlk + r * 64;
    const int C0 = c * 128;

    floatx16 acc[2][4];
#pragma unroll
    for (int mf = 0; mf < 2; ++mf)
#pragma unroll
        for (int nt = 0; nt < 4; ++nt)
#pragma unroll
            for (int i = 0; i < 16; ++i) acc[mf][nt][i] = 0.f;

    // A frag: row = ln (+32 for mf=1), k = q*8 + j
    const float* aptr0 = x + (size_t)(R0 + ln) * KDIM + q * 8;
    const float* aptr1 = aptr0 + (size_t)32 * KDIM;

    // B staging: wave w copies n in [w*64, w*64+64) for h and l
    const int nseg = w * 64;

    // ---- stage kt=0, prefetch A(0) ----
    ld_g2l_16(&Bs[0][0][nseg][0],      Wh + (size_t)nseg * 16 + lane * 8);
    ld_g2l_16(&Bs[0][0][nseg + 32][0], Wh + (size_t)(nseg + 32) * 16 + lane * 8);
    ld_g2l_16(&Bs[0][1][nseg][0],      Wl + (size_t)nseg * 16 + lane * 8);
    ld_g2l_16(&Bs[0][1][nseg + 32][0], Wl + (size_t)(nseg + 32) * 16 + lane * 8);
    floatx4 a[2][2];
    a[0][0] = *(const floatx4*)(aptr0);
    a[0][1] = *(const floatx4*)(aptr0 + 4);
    a[1][0] = *(const floatx4*)(aptr1);
    a[1][1] = *(const floatx4*)(aptr1 + 4);

#pragma unroll 2
    for (int kt = 0; kt < NKT; ++kt) {
        __syncthreads();               // stage(kt) complete; buf^1 readers done
        const int buf = kt & 1;
        if (kt + 1 < NKT) {            // stage(kt+1) into other buffer (async)
            const size_t g = (size_t)(kt + 1) * (NDIM * 16);
            ld_g2l_16(&Bs[buf ^ 1][0][nseg][0],      Wh + g + (size_t)nseg * 16 + lane * 8);
            ld_g2l_16(&Bs[buf ^ 1][0][nseg + 32][0], Wh + g + (size_t)(nseg + 32) * 16 + lane * 8);
            ld_g2l_16(&Bs[buf ^ 1][1][nseg][0],      Wl + g + (size_t)nseg * 16 + lane * 8);
            ld_g2l_16(&Bs[buf ^ 1][1][nseg + 32][0], Wl + g + (size_t)(nseg + 32) * 16 + lane * 8);
        }
        floatx4 pr[2][2];              // A prefetch for kt+1
        if (kt + 1 < NKT) {
            pr[0][0] = *(const floatx4*)(aptr0 + (kt + 1) * 16);
            pr[0][1] = *(const floatx4*)(aptr0 + (kt + 1) * 16 + 4);
            pr[1][0] = *(const floatx4*)(aptr1 + (kt + 1) * 16);
            pr[1][1] = *(const floatx4*)(aptr1 + (kt + 1) * 16 + 4);
        }
        // convert A(kt) to f16 hi/lo frags
        half8 ah[2], al[2];
#pragma unroll
        for (int mf = 0; mf < 2; ++mf) {
            const float av[8] = {a[mf][0][0], a[mf][0][1], a[mf][0][2], a[mf][0][3],
                                 a[mf][1][0], a[mf][1][1], a[mf][1][2], a[mf][1][3]};
#pragma unroll
            for (int j = 0; j < 8; ++j) {
                const _Float16 h = (_Float16)av[j];
                ah[mf][j] = h;
                al[mf][j] = (_Float16)(av[j] - (float)h);
            }
        }
#pragma unroll
        for (int nt = 0; nt < 4; ++nt) {
            const half8 bh = *(const half8*)&Bs[buf][0][C0 + nt * 32 + ln][q * 8];
            const half8 bl = *(const half8*)&Bs[buf][1][C0 + nt * 32 + ln][q * 8];
#pragma unroll
            for (int mf = 0; mf < 2; ++mf) {
                acc[mf][nt] = __builtin_amdgcn_mfma_f32_32x32x16_f16(ah[mf], bh, acc[mf][nt], 0, 0, 0);
                acc[mf][nt] = __builtin_amdgcn_mfma_f32_32x32x16_f16(al[mf], bh, acc[mf][nt], 0, 0, 0);
                acc[mf][nt] = __builtin_amdgcn_mfma_f32_32x32x16_f16(ah[mf], bl, acc[mf][nt], 0, 0, 0);
            }
        }
        if (kt + 1 < NKT) {
#pragma unroll
            for (int mf = 0; mf < 2; ++mf) { a[mf][0] = pr[mf][0]; a[mf][1] = pr[mf][1]; }
        }
    }

    // ---- epilogue: four 32-row phases; acc -> u_lds fp32, then routing ----
    // C/D layout 32x32: col = ln, row = (reg&3) + 8*(reg>>2) + 4*q
    // routing lane map: cap = lane>>2 (bits 2..5), dgrp = lane&3 (bits 0..1)
    // NOTE: p-loop MUST be unrolled so acc[p&1] is compile-time (else spill).
    const int dgrp = lane & 3;
#pragma unroll
    for (int p = 0; p < 4; ++p) {
        __syncthreads();               // previous-phase reads / K-loop reads done
        if (r == (p >> 1)) {
            const int mf = p & 1;
#pragma unroll
            for (int nt = 0; nt < 4; ++nt)
#pragma unroll
                for (int reg = 0; reg < 16; ++reg)
                    u_lds[(reg & 3) + 8 * (reg >> 2) + 4 * q][C0 + nt * 32 + ln] = acc[mf][nt][reg];
        }
        __syncthreads();
#pragma unroll 1
        for (int ri = 0; ri < 4; ++ri) {
            const int rl = w * 4 + ri;               // local row 0..31
            const floatx4 ua = *(const floatx4*)&u_lds[rl][lane * 8];
            const floatx4 ub = *(const floatx4*)&u_lds[rl][lane * 8 + 4];
            const float u8[8] = {ua[0], ua[1], ua[2], ua[3],
                                 ub[0], ub[1], ub[2], ub[3]};
            float b_own = 0.f;
            float v[8];
#pragma unroll
            for (int it = 0; it < 3; ++it) {
                float c_own;
                if (it == 0) {
                    c_own = 1.0f / 16.0f;            // softmax of zeros
                } else {
                    const float m = cap_max(b_own);
                    const float e = __expf(b_own - m);
                    const float ssum = cap_sum(e);
                    c_own = e / ssum;
                }
                float s[8];
#pragma unroll
                for (int j = 0; j < 8; ++j) s[j] = c_own * u8[j];
                // allreduce each s[j] over capsules, steps interleaved for ILP
#pragma unroll
                for (int j = 0; j < 8; ++j) s[j] += dpp_mov<ROR4>(s[j]);
#pragma unroll
                for (int j = 0; j < 8; ++j) s[j] += dpp_mov<ROR8>(s[j]);
#pragma unroll
                for (int j = 0; j < 8; ++j) s[j] += swz_xor<16>(s[j]);
#pragma unroll
                for (int j = 0; j < 8; ++j) s[j] += __shfl_xor(s[j], 32);
                float nrm = 0.f;
#pragma unroll
                for (int j = 0; j < 8; ++j) nrm = fmaf(s[j], s[j], nrm);
                nrm = dg_sum(nrm);
                const float scale = nrm / ((1.f + nrm) * (sqrtf(nrm) + EPS_F));
#pragma unroll
                for (int j = 0; j < 8; ++j) v[j] = scale * s[j];
                if (it < 2) {
                    float dot = 0.f;
#pragma unroll
                    for (int j = 0; j < 8; ++j) dot = fmaf(u8[j], v[j], dot);
                    dot = dg_sum(dot);
                    b_own += dot;
                }
            }
            if (lane < 4) {
                float4* o = (float4*)(out + (size_t)(rowBlk + p * 32 + rl) * OUT_DIM
                                      + dgrp * 8);
                o[0] = make_float4(v[0], v[1], v[2], v[3]);
                o[1] = make_float4(v[4], v[5], v[6], v[7]);
            }
        }
    }
}

extern "C" void kernel_launch(void* const* d_in, const int* in_sizes, int n_in,
                              void* d_out, int out_size, void* d_ws, size_t ws_size,
                              hipStream_t stream) {
    const float* x = (const float*)d_in[0];   // [32768, 512]
    const float* W = (const float*)d_in[1];   // [512, 512]
    float* out = (float*)d_out;               // [32768, 32]
    _Float16* Wh = (_Float16*)d_ws;           // [32][512][16] f16 tiled
    _Float16* Wl = Wh + (size_t)NDIM * KDIM;

    prep_w<<<dim3(16, 16), dim3(32, 8), 0, stream>>>(W, Wh, Wl);
    capsule_mfma<<<dim3(BATCH / 128), dim3(512), 0, stream>>>(x, Wh, Wl, out);
}

// Round 8
// 157.041 us; speedup vs baseline: 2.8460x; 1.0671x over previous
//
#include <hip/hip_runtime.h>
#include <math.h>

// CapsuleLayer: u = x@W via split-precision f16 MFMA (xh@Wh + xl@Wh + xh@Wl),
// 32x32x16, dbuf LDS staging for BOTH operands.
// R8: A now staged through LDS. Rationale (R7 counters): MFMA busy == floor
// (21 us) but util only 21% -> latency-bound on the A row-gather (lane=row
// frag loads touch 64 distinct 2KB-strided lines per instr). Fix: coalesced
// float4 loads (16 x 64B segments/wave), convert to f16 hi/lo ONCE per
// element (dedups the 4x-replicated cvt), ds_write into As[2][128][64B] with
// XOR-swizzled 16B chunks {h0,h1,l0,l1} at pos = c ^ ((row>>1)&3) ->
// conflict-free b128 frag reads (bank starts cycle 0,16,4,20,8,24,12,28).
//
// x: [32768,512] fp32  W: [512,512] fp32  v: [32768,32] fp32
// prep_w: W[k][n] -> Wh/Wl tiled [kt][n][k%16] f16 in d_ws (1 MB).
// Main: block = 512 thr (8 waves), tile 128 rows x 512 cols, grid 256.
// Wave (r=w>>2, c=w&3): rows r*64 + mf*32, cols c*128. acc = 2x4x16 fp32.
// Per kt: 1 barrier, 4 B-DMA + 1 A-load + 2 ds_write (stage kt+1),
// 12 ds_read_b128, 24 MFMA. Epilogue: 4 phases of 32 rows via u_lds.

#define BATCH   32768
#define KDIM    512
#define NDIM    512
#define OUT_DIM 32
#define EPS_F   1e-8f
#define NKT     32            // K tiles of 16

typedef _Float16 half8  __attribute__((ext_vector_type(8)));
typedef _Float16 half4t __attribute__((ext_vector_type(4)));
typedef float   floatx4 __attribute__((ext_vector_type(4)));
typedef float  floatx16 __attribute__((ext_vector_type(16)));

// ---- cross-lane helpers (R7, proven) ----
template <int CTRL>
__device__ __forceinline__ float dpp_mov(float x) {
    return __int_as_float(__builtin_amdgcn_mov_dpp(__float_as_int(x), CTRL, 0xF, 0xF, true));
}
template <int XMASK>   // XMASK <= 31: ds_swizzle BitMode xor (within 32-lane group)
__device__ __forceinline__ float swz_xor(float x) {
    return __int_as_float(__builtin_amdgcn_ds_swizzle(__float_as_int(x), (XMASK << 10) | 31));
}
#define ROR4  0x124  // row_ror:4
#define ROR8  0x128  // row_ror:8
#define QXOR1 0xB1   // quad_perm [1,0,3,2] = xor 1
#define QXOR2 0x4E   // quad_perm [2,3,0,1] = xor 2

__device__ __forceinline__ float cap_sum(float x) {
    x += dpp_mov<ROR4>(x);
    x += dpp_mov<ROR8>(x);
    x += swz_xor<16>(x);
    x += __shfl_xor(x, 32);          // lane bit 5: bpermute only
    return x;
}
__device__ __forceinline__ float cap_max(float x) {
    x = fmaxf(x, dpp_mov<ROR4>(x));
    x = fmaxf(x, dpp_mov<ROR8>(x));
    x = fmaxf(x, swz_xor<16>(x));
    x = fmaxf(x, __shfl_xor(x, 32));
    return x;
}
__device__ __forceinline__ float dg_sum(float x) {
    x += dpp_mov<QXOR1>(x);
    x += dpp_mov<QXOR2>(x);
    return x;
}

// ---- prep: W[k][n] fp32 -> Wh/Wl [kt][n][k%16] f16 hi/lo split ----
__global__ void prep_w(const float* __restrict__ W, _Float16* __restrict__ Wh,
                       _Float16* __restrict__ Wl) {
    __shared__ float tile[32][33];
    const int tx = threadIdx.x, ty = threadIdx.y;      // block (32, 8)
    const int n0 = blockIdx.x * 32, k0 = blockIdx.y * 32;
#pragma unroll
    for (int i = 0; i < 4; ++i)
        tile[ty + 8 * i][tx] = W[(size_t)(k0 + ty + 8 * i) * NDIM + n0 + tx];
    __syncthreads();
#pragma unroll
    for (int i = 0; i < 4; ++i) {
        const int k = k0 + tx, n = n0 + ty + 8 * i;
        const float v = tile[tx][ty + 8 * i];          // = W[k][n]
        const _Float16 h = (_Float16)v;
        const _Float16 l = (_Float16)(v - (float)h);
        const size_t off = (size_t)(k >> 4) * (NDIM * 16) + (size_t)n * 16 + (k & 15);
        Wh[off] = h;
        Wl[off] = l;
    }
}

__device__ __forceinline__ void ld_g2l_16(void* lds_base_uniform, const void* g) {
    __builtin_amdgcn_global_load_lds(
        (const __attribute__((address_space(1))) void*)g,
        (__attribute__((address_space(3))) void*)lds_base_uniform, 16, 0, 0);
}

#define AS_OFF 65536          // As starts after Bs (64 KB)

__global__ __launch_bounds__(512, 2)
void capsule_mfma(const float* __restrict__ x, const _Float16* __restrict__ Wh,
                  const _Float16* __restrict__ Wl, float* __restrict__ out) {
    __shared__ __align__(16) char smem[81920];   // Bs 64K + As 16K; u_lds unions low 66.56K
    _Float16 (*Bs)[2][NDIM][16] = (_Float16 (*)[2][NDIM][16])smem;  // [buf][h/l][n][k']
    float (*u_lds)[520] = (float (*)[520])smem;

    const int tid  = threadIdx.x;
    const int w    = tid >> 6;          // wave 0..7
    const int lane = tid & 63;
    const int r = w >> 2, c = w & 3;    // row-half / col-group
    const int ln = lane & 31, q = lane >> 5;
    const int rowBlk = blockIdx.x * 128;
    const int C0 = c * 128;

    floatx16 acc[2][4];
#pragma unroll
    for (int mf = 0; mf < 2; ++mf)
#pragma unroll
        for (int nt = 0; nt < 4; ++nt)
#pragma unroll
            for (int i = 0; i < 16; ++i) acc[mf][nt][i] = 0.f;

    // ---- A staging assignment: thread -> (row, k-quarter), coalesced ----
    const int srow = tid >> 2;          // 0..127
    const int skq  = tid & 3;           // quarter: 4 floats
    const float* sga = x + (size_t)(rowBlk + srow) * KDIM + skq * 4;
    const int ssw = (srow >> 1) & 3;    // swizzle key
    // chunk ids: h quarter kq -> c=kq>>1; l -> c=2^(kq>>1). pos = c ^ ssw.
    const int swoff_h = srow * 64 + (((skq >> 1) ^ ssw) * 16) + (skq & 1) * 8;
    const int swoff_l = srow * 64 + ((((skq >> 1) ^ 2) ^ ssw) * 16) + (skq & 1) * 8;

    // ---- A frag read offsets (per mf, per q): pos_h = q^asw, pos_l = (q^2)^asw
    int afr_h[2], afr_l[2];
#pragma unroll
    for (int mf = 0; mf < 2; ++mf) {
        const int ar = r * 64 + mf * 32 + ln;           // local row 0..127
        const int asw = (ar >> 1) & 3;
        afr_h[mf] = ar * 64 + ((q ^ asw) * 16);
        afr_l[mf] = ar * 64 + (((q ^ 2) ^ asw) * 16);
    }

    // B staging: wave w copies n in [w*64, w*64+64) for h and l
    const int nseg = w * 64;

    // ---- stage kt=0 ----
    {
        const floatx4 v0 = *(const floatx4*)sga;
        half4t h4, l4;
#pragma unroll
        for (int j = 0; j < 4; ++j) {
            h4[j] = (_Float16)v0[j];
            l4[j] = (_Float16)(v0[j] - (float)h4[j]);
        }
        *(half4t*)(smem + AS_OFF + swoff_h) = h4;
        *(half4t*)(smem + AS_OFF + swoff_l) = l4;
    }
    ld_g2l_16(&Bs[0][0][nseg][0],      Wh + (size_t)nseg * 16 + lane * 8);
    ld_g2l_16(&Bs[0][0][nseg + 32][0], Wh + (size_t)(nseg + 32) * 16 + lane * 8);
    ld_g2l_16(&Bs[0][1][nseg][0],      Wl + (size_t)nseg * 16 + lane * 8);
    ld_g2l_16(&Bs[0][1][nseg + 32][0], Wl + (size_t)(nseg + 32) * 16 + lane * 8);

#pragma unroll 2
    for (int kt = 0; kt < NKT; ++kt) {
        __syncthreads();               // stage(kt) complete (vm + lgkm drained)
        const int buf = kt & 1;
        floatx4 sv;
        if (kt + 1 < NKT) {            // stage(kt+1): B async DMA + A global load
            const size_t g = (size_t)(kt + 1) * (NDIM * 16);
            ld_g2l_16(&Bs[buf ^ 1][0][nseg][0],      Wh + g + (size_t)nseg * 16 + lane * 8);
            ld_g2l_16(&Bs[buf ^ 1][0][nseg + 32][0], Wh + g + (size_t)(nseg + 32) * 16 + lane * 8);
            ld_g2l_16(&Bs[buf ^ 1][1][nseg][0],      Wl + g + (size_t)nseg * 16 + lane * 8);
            ld_g2l_16(&Bs[buf ^ 1][1][nseg + 32][0], Wl + g + (size_t)(nseg + 32) * 16 + lane * 8);
            sv = *(const floatx4*)(sga + (kt + 1) * 16);
        }
        // A frags from LDS (swizzled, conflict-free)
        const int abase = AS_OFF + buf * 8192;
        half8 ah[2], al[2];
#pragma unroll
        for (int mf = 0; mf < 2; ++mf) {
            ah[mf] = *(const half8*)(smem + abase + afr_h[mf]);
            al[mf] = *(const half8*)(smem + abase + afr_l[mf]);
        }
#pragma unroll
        for (int nt = 0; nt < 4; ++nt) {
            const half8 bh = *(const half8*)&Bs[buf][0][C0 + nt * 32 + ln][q * 8];
            const half8 bl = *(const half8*)&Bs[buf][1][C0 + nt * 32 + ln][q * 8];
#pragma unroll
            for (int mf = 0; mf < 2; ++mf) {
                acc[mf][nt] = __builtin_amdgcn_mfma_f32_32x32x16_f16(ah[mf], bh, acc[mf][nt], 0, 0, 0);
                acc[mf][nt] = __builtin_amdgcn_mfma_f32_32x32x16_f16(al[mf], bh, acc[mf][nt], 0, 0, 0);
                acc[mf][nt] = __builtin_amdgcn_mfma_f32_32x32x16_f16(ah[mf], bl, acc[mf][nt], 0, 0, 0);
            }
        }
        if (kt + 1 < NKT) {            // A cvt + ds_write into other buffer
            half4t h4, l4;
#pragma unroll
            for (int j = 0; j < 4; ++j) {
                h4[j] = (_Float16)sv[j];
                l4[j] = (_Float16)(sv[j] - (float)h4[j]);
            }
            const int nbase = AS_OFF + (buf ^ 1) * 8192;
            *(half4t*)(smem + nbase + swoff_h) = h4;
            *(half4t*)(smem + nbase + swoff_l) = l4;
        }
    }

    // ---- epilogue: four 32-row phases; acc -> u_lds fp32, then routing ----
    // C/D layout 32x32: col = ln, row = (reg&3) + 8*(reg>>2) + 4*q
    // routing lane map: cap = lane>>2 (bits 2..5), dgrp = lane&3 (bits 0..1)
    // p-loop MUST be unrolled so acc[p&1] is compile-time (else spill — R6!).
    const int dgrp = lane & 3;
#pragma unroll
    for (int p = 0; p < 4; ++p) {
        __syncthreads();               // previous-phase reads / K-loop reads done
        if (r == (p >> 1)) {
            const int mf = p & 1;
#pragma unroll
            for (int nt = 0; nt < 4; ++nt)
#pragma unroll
                for (int reg = 0; reg < 16; ++reg)
                    u_lds[(reg & 3) + 8 * (reg >> 2) + 4 * q][C0 + nt * 32 + ln] = acc[mf][nt][reg];
        }
        __syncthreads();
#pragma unroll 1
        for (int ri = 0; ri < 4; ++ri) {
            const int rl = w * 4 + ri;               // local row 0..31
            const floatx4 ua = *(const floatx4*)&u_lds[rl][lane * 8];
            const floatx4 ub = *(const floatx4*)&u_lds[rl][lane * 8 + 4];
            const float u8[8] = {ua[0], ua[1], ua[2], ua[3],
                                 ub[0], ub[1], ub[2], ub[3]};
            float b_own = 0.f;
            float v[8];
#pragma unroll
            for (int it = 0; it < 3; ++it) {
                float c_own;
                if (it == 0) {
                    c_own = 1.0f / 16.0f;            // softmax of zeros
                } else {
                    const float m = cap_max(b_own);
                    const float e = __expf(b_own - m);
                    const float ssum = cap_sum(e);
                    c_own = e / ssum;
                }
                float s[8];
#pragma unroll
                for (int j = 0; j < 8; ++j) s[j] = c_own * u8[j];
#pragma unroll
                for (int j = 0; j < 8; ++j) s[j] += dpp_mov<ROR4>(s[j]);
#pragma unroll
                for (int j = 0; j < 8; ++j) s[j] += dpp_mov<ROR8>(s[j]);
#pragma unroll
                for (int j = 0; j < 8; ++j) s[j] += swz_xor<16>(s[j]);
#pragma unroll
                for (int j = 0; j < 8; ++j) s[j] += __shfl_xor(s[j], 32);
                float nrm = 0.f;
#pragma unroll
                for (int j = 0; j < 8; ++j) nrm = fmaf(s[j], s[j], nrm);
                nrm = dg_sum(nrm);
                const float scale = nrm / ((1.f + nrm) * (sqrtf(nrm) + EPS_F));
#pragma unroll
                for (int j = 0; j < 8; ++j) v[j] = scale * s[j];
                if (it < 2) {
                    float dot = 0.f;
#pragma unroll
                    for (int j = 0; j < 8; ++j) dot = fmaf(u8[j], v[j], dot);
                    dot = dg_sum(dot);
                    b_own += dot;
                }
            }
            if (lane < 4) {
                float4* o = (float4*)(out + (size_t)(rowBlk + p * 32 + rl) * OUT_DIM
                                      + dgrp * 8);
                o[0] = make_float4(v[0], v[1], v[2], v[3]);
                o[1] = make_float4(v[4], v[5], v[6], v[7]);
            }
        }
    }
}

extern "C" void kernel_launch(void* const* d_in, const int* in_sizes, int n_in,
                              void* d_out, int out_size, void* d_ws, size_t ws_size,
                              hipStream_t stream) {
    const float* x = (const float*)d_in[0];   // [32768, 512]
    const float* W = (const float*)d_in[1];   // [512, 512]
    float* out = (float*)d_out;               // [32768, 32]
    _Float16* Wh = (_Float16*)d_ws;           // [32][512][16] f16 tiled
    _Float16* Wl = Wh + (size_t)NDIM * KDIM;

    prep_w<<<dim3(16, 16), dim3(32, 8), 0, stream>>>(W, Wh, Wl);
    capsule_mfma<<<dim3(BATCH / 128), dim3(512), 0, stream>>>(x, Wh, Wl, out);
}